// Round 8
// baseline (126.853 us; speedup 1.0000x reference)
//
#include <hip/hip_runtime.h>
#include <stdint.h>

// ClusterHead: P = softmax_k( x . c_k - 0.5*||c_k||^2 )   (||x||^2 cancels)
// R8 = R7 + non-temporal hints on streaming traffic (x loads, out stores).
// Theory: x/out streams thrash the per-XCD L2, evicting the 2MB B-pack, so
// B reads (1GB total reuse traffic) fall to L3 -> the hidden ~100us. NT
// hints keep L2 clean; B-pack stays L2-resident.
//
// fp16 split, TWO terms: logits ~= x_h . (c_h + c_l); 32x32x16 f16 MFMA.
// B global->VGPR reg double-buffer, A in LDS ping-pong, 1 barrier/slice.

namespace {
constexpr int N_ROWS  = 32768;
constexpr int K_CL    = 1024;
constexpr int D_DIM   = 512;
constexpr int BM      = 64;
constexpr int THREADS = 512;
constexpr int WAVES   = 8;
constexpr int NSLICE  = 16;     // k-slices of 32
}

typedef _Float16 f16_t;
typedef _Float16 f16x8 __attribute__((ext_vector_type(8)));
typedef _Float16 f16x4 __attribute__((ext_vector_type(4)));
typedef float    f32x16 __attribute__((ext_vector_type(16)));
typedef float    f32x4v __attribute__((ext_vector_type(4)));

// ---- prep: fp16 hi/lo B-pack + bias = -0.5*||c||^2 (fp32 exact)
__global__ __launch_bounds__(64) void prep_kernel(const float* __restrict__ centers,
                                                  f16_t* __restrict__ bpack,
                                                  float* __restrict__ bias) {
  const int col = blockIdx.x, lane = threadIdx.x;
  const int t  = lane >> 2;          // k-slice of this lane's 8 d's
  const int ks = (lane >> 1) & 1;    // 16-k group
  const int kh = lane & 1;           // 8-k half
  const float* src = centers + (size_t)col * D_DIM + lane * 8;
  f16x8 hi, lo;
  float ssq = 0.f;
  #pragma unroll
  for (int i = 0; i < 8; ++i) {
    float v = src[i];
    ssq += v * v;
    f16_t h = (f16_t)v;
    hi[i] = h;
    lo[i] = (f16_t)(v - (float)h);
  }
  const int jh = col >> 9, cb = (col & 511) >> 5, c32 = col & 31;
  const size_t off = ((size_t)ks * 16 + cb) * 512 + (c32 * 2 + kh) * 8;  // halfwords
  *(f16x8*)(bpack + (size_t)(4 * t + jh)     * 16384 + off) = hi;
  *(f16x8*)(bpack + (size_t)(4 * t + 2 + jh) * 16384 + off) = lo;
  for (int o = 32; o; o >>= 1) ssq += __shfl_down(ssq, o, 64);
  if (lane == 0) bias[col] = -0.5f * ssq;
}

// ---- main fused kernel: 64 rows x 1024 cols per block ----
__global__ __launch_bounds__(THREADS, 2) void cluster_kernel(
    const float* __restrict__ x, const f16_t* __restrict__ bpack,
    const float* __restrict__ bias, float* __restrict__ out) {
  __shared__ f16_t Abuf[2][4][64][8];   // [slice parity][kh2][row][e]  8KB
  __shared__ float red[WAVES * BM];     // 2KB
  __shared__ float fin[BM];

  const int tid  = threadIdx.x;
  const int wid  = tid >> 6;
  const int lane = tid & 63;
  const int l31  = lane & 31;
  const int h    = lane >> 5;
  const int brow = blockIdx.x * BM;
  const int xrow = tid >> 3, q8 = tid & 7;

  f32x16 acc[2][4];
  #pragma unroll
  for (int rb = 0; rb < 2; ++rb)
    #pragma unroll
    for (int cc = 0; cc < 4; ++cc)
      #pragma unroll
      for (int e = 0; e < 16; ++e) acc[rb][cc][e] = 0.f;

  // per-lane byte base into a sub-image (wave's 2 col-blocks start at wid*2048)
  const char* bbase = (const char*)bpack + wid * 2048 + (l31 * 2 + h) * 16;
  const float* xbase = x + (size_t)(brow + xrow) * D_DIM + q8 * 4;

#define LOADB(S, DST)                                                          \
  {                                                                            \
    const char* p_ = bbase + (size_t)((S) & 63) * 32768;                       \
    (DST)[0] = *(const f16x8*)(p_);            /* ks0, cb even */              \
    (DST)[1] = *(const f16x8*)(p_ + 1024);     /* ks0, cb odd  */              \
    (DST)[2] = *(const f16x8*)(p_ + 16384);    /* ks1, cb even */              \
    (DST)[3] = *(const f16x8*)(p_ + 17408);    /* ks1, cb odd  */              \
  }
#define CONVERT(XV, PAR)                                                       \
  {                                                                            \
    f16x4 h4_;                                                                 \
    h4_[0] = (f16_t)(XV).x; h4_[1] = (f16_t)(XV).y;                            \
    h4_[2] = (f16_t)(XV).z; h4_[3] = (f16_t)(XV).w;                            \
    *(f16x4*)&Abuf[(PAR)][q8 >> 1][xrow][(q8 & 1) * 4] = h4_;                  \
  }
#define COMPUTE(B, JH)                                                         \
  {                                                                            \
    _Pragma("unroll")                                                          \
    for (int ks_ = 0; ks_ < 2; ++ks_)                                          \
      _Pragma("unroll")                                                        \
      for (int c2_ = 0; c2_ < 2; ++c2_) {                                      \
        _Pragma("unroll")                                                      \
        for (int rb_ = 0; rb_ < 2; ++rb_)                                      \
          acc[rb_][(JH) * 2 + c2_] = __builtin_amdgcn_mfma_f32_32x32x16_f16(   \
              a[rb_][ks_], (B)[ks_ * 2 + c2_], acc[rb_][(JH) * 2 + c2_],       \
              0, 0, 0);                                                        \
      }                                                                        \
  }

  f16x8 bcur[4], bnxt[4];

  // ---- prologue: convert x slice 0, prefetch B(0) ----
  {
    f32x4v xv0 = __builtin_nontemporal_load((const f32x4v*)xbase);
    CONVERT(xv0, 0)
  }
  LOADB(0, bcur)
  __syncthreads();

  f16x8 a[2][2];

  // ---- main loop: 16 slices x 4 sub-images, barrier once per slice ----
  #pragma unroll 1
  for (int t = 0; t < NSLICE; ++t) {
    #pragma unroll
    for (int rb = 0; rb < 2; ++rb)
      #pragma unroll
      for (int ks = 0; ks < 2; ++ks)
        a[rb][ks] = *(const f16x8*)&Abuf[t & 1][ks * 2 + h][rb * 32 + l31][0];

    const int s0 = 4 * t;

    // J0: c_hi half0
    LOADB(s0 + 1, bnxt)
    f32x4v xv = __builtin_nontemporal_load(
        (const f32x4v*)(xbase + ((t + 1) & 15) * 32));
    COMPUTE(bcur, 0)

    // J1: c_hi half1
    LOADB(s0 + 2, bcur)
    COMPUTE(bnxt, 1)

    // J2: c_lo half0; convert x(t+1)
    LOADB(s0 + 3, bnxt)
    CONVERT(xv, (t + 1) & 1)
    COMPUTE(bcur, 0)

    // J3: c_lo half1; prefetch next slice (wrapped dummy at tail)
    LOADB((s0 + 4) & 63, bcur)
    COMPUTE(bnxt, 1)

    __syncthreads();   // A(t+1) visible; bounds wave skew
  }

  // ---- epilogue: fused softmax over 1024 columns ----
  // col(cc) = (cc>>1)*512 + wid*64 + (cc&1)*32 + l31
  // row(rb,reg) = rb*32 + (reg&3) + 8*(reg>>2) + 4*h
  float bcol[4];
  #pragma unroll
  for (int cc = 0; cc < 4; ++cc)
    bcol[cc] = bias[(cc >> 1) * 512 + wid * 64 + (cc & 1) * 32 + l31];

  float rr[2][16];
  #pragma unroll
  for (int rb = 0; rb < 2; ++rb)
    #pragma unroll
    for (int reg = 0; reg < 16; ++reg) {
      float m = -3.0e38f;
      #pragma unroll
      for (int cc = 0; cc < 4; ++cc) {
        float v = acc[rb][cc][reg] + bcol[cc];
        acc[rb][cc][reg] = v;
        m = fmaxf(m, v);
      }
      m = fmaxf(m, __shfl_xor(m, 1, 64));
      m = fmaxf(m, __shfl_xor(m, 2, 64));
      m = fmaxf(m, __shfl_xor(m, 4, 64));
      m = fmaxf(m, __shfl_xor(m, 8, 64));
      m = fmaxf(m, __shfl_xor(m, 16, 64));
      rr[rb][reg] = m;
    }
  if (l31 == 0) {
    #pragma unroll
    for (int rb = 0; rb < 2; ++rb)
      #pragma unroll
      for (int reg = 0; reg < 16; ++reg)
        red[wid * BM + rb * 32 + (reg & 3) + 8 * (reg >> 2) + 4 * h] = rr[rb][reg];
  }
  __syncthreads();
  if (tid < BM) {
    float m = red[tid];
    #pragma unroll
    for (int w = 1; w < WAVES; ++w) m = fmaxf(m, red[w * BM + tid]);
    fin[tid] = m;
  }
  __syncthreads();

  #pragma unroll
  for (int rb = 0; rb < 2; ++rb)
    #pragma unroll
    for (int reg = 0; reg < 16; ++reg) {
      const float m = fin[rb * 32 + (reg & 3) + 8 * (reg >> 2) + 4 * h];
      float s = 0.f;
      #pragma unroll
      for (int cc = 0; cc < 4; ++cc) {
        float e = __expf(acc[rb][cc][reg] - m);
        acc[rb][cc][reg] = e;
        s += e;
      }
      s += __shfl_xor(s, 1, 64);
      s += __shfl_xor(s, 2, 64);
      s += __shfl_xor(s, 4, 64);
      s += __shfl_xor(s, 8, 64);
      s += __shfl_xor(s, 16, 64);
      rr[rb][reg] = s;
    }
  __syncthreads();   // fin(max) reads done before red overwrite
  if (l31 == 0) {
    #pragma unroll
    for (int rb = 0; rb < 2; ++rb)
      #pragma unroll
      for (int reg = 0; reg < 16; ++reg)
        red[wid * BM + rb * 32 + (reg & 3) + 8 * (reg >> 2) + 4 * h] = rr[rb][reg];
  }
  __syncthreads();
  if (tid < BM) {
    float s = 0.f;
    #pragma unroll
    for (int w = 0; w < WAVES; ++w) s += red[w * BM + tid];
    fin[tid] = 1.0f / s;
  }
  __syncthreads();

  #pragma unroll
  for (int rb = 0; rb < 2; ++rb)
    #pragma unroll
    for (int reg = 0; reg < 16; ++reg) {
      const int row = rb * 32 + (reg & 3) + 8 * (reg >> 2) + 4 * h;
      const float rs = fin[row];
      #pragma unroll
      for (int cc = 0; cc < 4; ++cc) {
        const int col = (cc >> 1) * 512 + wid * 64 + (cc & 1) * 32 + l31;
        __builtin_nontemporal_store(acc[rb][cc][reg] * rs,
                                    &out[(size_t)(brow + row) * K_CL + col]);
      }
    }
}

extern "C" void kernel_launch(void* const* d_in, const int* in_sizes, int n_in,
                              void* d_out, int out_size, void* d_ws, size_t ws_size,
                              hipStream_t stream) {
  const float* x       = (const float*)d_in[0];   // [32768, 512] fp32
  const float* centers = (const float*)d_in[1];   // [1024, 512] fp32
  float* out = (float*)d_out;                     // [32768, 1024] fp32

  f16_t* bpack = (f16_t*)d_ws;                                   // 64*32KB = 2MB
  float* bias  = (float*)((char*)d_ws + (size_t)64 * 32768);     // 4KB

  prep_kernel<<<K_CL, 64, 0, stream>>>(centers, bpack, bias);
  cluster_kernel<<<N_ROWS / BM, THREADS, 0, stream>>>(x, bpack, bias, out);
}